// Round 13
// baseline (433.668 us; speedup 1.0000x reference)
//
#include <hip/hip_runtime.h>
#include <math.h>

// Problem constants: N=8, C=128, H=64, W=64, B=N*W=512, ADJ=33, G=8, GP=16
constexpr float EPSV = 1e-5f;
typedef unsigned short u16;
using bf16x8 = __attribute__((ext_vector_type(8))) short;
using f32x4  = __attribute__((ext_vector_type(4))) float;

// ---------------- workspace layout (offsets in floats) ----------------
constexpr size_t F_W127  = 0;
constexpr size_t F_W64   = F_W127 + 4224;
constexpr size_t F_QKVST = F_W64  + 2112;
constexpr size_t F_SIMST = F_QKVST+ 512;
constexpr size_t F_SOST  = F_SIMST+ 384;
constexpr size_t F_INST  = F_SOST + 512;
constexpr size_t F_POSTMP= F_INST + 2048;          // 134112 (alias: w1b/w2b after pos2)
constexpr size_t F_POS   = F_POSTMP + 134112;      // 34848 (alias: wT before pos2)
constexpr size_t F_QKV   = F_POS  + 34848;         // qkvT [512][64][256] = 8388608 (alias: SO)
constexpr size_t F_QKVR  = F_QKV  + 8388608;       // qkvrT [512][33][256] = 4325376
constexpr size_t F_SIM   = F_QKVR + 4325376;       // 13381632 (alias: XP early, BNP)
constexpr size_t F_PART6 = F_SIM  + 13381632;      // 24576 (alias: so-stats partials after attn)
constexpr size_t F_VAP   = F_PART6 + 24576;        // Vap fp32 [512][8][16][9]x4 = 2359296
constexpr size_t F_VEH   = F_PART6 + 4460544;      // velp u16[36864] = 18432 f
constexpr size_t F_XNT   = F_VEH  + 33792;         // xnT bf16 = 2097152 f
constexpr size_t F_KET   = F_XNT  + 2097152;       // keT 8712
constexpr size_t F_SO    = F_QKV;
constexpr size_t F_XP    = F_SIM;
constexpr size_t F_BNP   = F_SIM;
constexpr size_t F_H1    = F_SIM + 4194304;        // h1T bf16 = 8388608 f
constexpr size_t F_WT    = F_POS;
constexpr size_t F_W1B   = F_POSTMP;               // 32768 floats
constexpr size_t F_W2B   = F_POSTMP + 32768;       // 32768 floats

__device__ __forceinline__ void fma4(float4& a, const float4& h, float s){
  a.x += h.x*s; a.y += h.y*s; a.z += h.z*s; a.w += h.w*s;
}
__device__ __forceinline__ u16 f2b(float x){      // fp32 -> bf16 RNE
  unsigned u = __float_as_uint(x);
  return (u16)((u + 0x7FFFu + ((u>>16)&1u)) >> 16);
}
__device__ __forceinline__ float b2f(u16 u){
  return __uint_as_float(((unsigned)u) << 16);
}

// ---- compile-time 33->64 upsample tables ----
struct UpT { int j0[64]; float fj[64]; };
constexpr UpT mkUp(){
  UpT t{};
  for (int o=0;o<64;++o){
    float x = ((float)o + 0.5f)*0.515625f - 0.5f;
    if (x < 0.f) x = 0.f;
    if (x > 32.f) x = 32.f;
    int j = (int)x; if (j > 31) j = 31;
    t.j0[o] = j; t.fj[o] = x - (float)j;
  }
  return t;
}
constexpr UpT UT = mkUp();

__device__ __forceinline__ void upfac(int o, int& j0, float& f){
  float x = ((float)o + 0.5f)*0.515625f - 0.5f;
  x = fminf(fmaxf(x, 0.f), 32.f);
  int j = (int)x; j = j < 31 ? j : 31;
  j0 = j; f = x - (float)j;
}

// ---------------- resize weight tables ----------------
__global__ void k_tables(float* __restrict__ W127, float* __restrict__ W64){
  int i = threadIdx.x;
  if (i < 33){
    const float inv = 127.0f/33.0f;
    float x = ((float)i + 0.5f)*inv - 0.5f;
    float s = 0.f;
    for (int j=0;j<127;++j){ float w = 1.0f - fabsf((float)j - x)/inv; w = fmaxf(w,0.f); W127[i*127+j]=w; s+=w; }
    float r = 1.0f/s;
    for (int j=0;j<127;++j) W127[i*127+j] *= r;
  } else if (i < 66){
    int ii = i-33;
    const float inv = 64.0f/33.0f;
    float x = ((float)ii + 0.5f)*inv - 0.5f;
    float s=0.f;
    for (int j=0;j<64;++j){ float w = 1.0f - fabsf((float)j - x)/inv; w=fmaxf(w,0.f); W64[ii*64+j]=w; s+=w; }
    float r=1.0f/s;
    for (int j=0;j<64;++j) W64[ii*64+j]*=r;
  }
}

// ---------------- generic 32x32-tiled transpose ----------------
__global__ __launch_bounds__(256) void k_tr(const float* __restrict__ src, float* __restrict__ dst,
                                            int R, int C){
  __shared__ float T[32][33];
  int r0 = blockIdx.x*32, c0 = blockIdx.y*32;
  int tx = threadIdx.x&31, ty = threadIdx.x>>5;
  #pragma unroll
  for (int q=0;q<4;++q){ int r = ty + q*8; T[r][tx] = src[(r0+r)*C + c0+tx]; }
  __syncthreads();
  #pragma unroll
  for (int q=0;q<4;++q){ int c = ty + q*8; dst[(c0+c)*R + r0+tx] = T[tx][c]; }
}

// ---------------- fp32 -> bf16 elementwise convert ----------------
__global__ void k_cvtb(const float* __restrict__ src, u16* __restrict__ dst, int n){
  int id = blockIdx.x*256 + threadIdx.x;
  if (id < n) dst[id] = f2b(src[id]);
}

// ---------------- x (N,C,H,W) -> xp (N*W, C, H) ----------------
__global__ __launch_bounds__(256) void k_xt(const float* __restrict__ x, float* __restrict__ xp){
  __shared__ float T[64][65];
  int n = blockIdx.x>>7, c = blockIdx.x&127;
  const float* src = x + ((size_t)(n*128 + c))*4096;
  int tid = threadIdx.x;
  for (int e=tid;e<4096;e+=256){ int h=e>>6, w=e&63; T[h][w] = src[e]; }
  __syncthreads();
  for (int e=tid;e<4096;e+=256){
    int w=e>>6, h=e&63;
    xp[((size_t)((n*64+w)*128 + c))*64 + h] = T[h][w];
  }
}

// ---------------- QKV projection GEMM -> qkvT[b][l][o] ----------------
__global__ __launch_bounds__(256) void k_qkv(const float* __restrict__ xp, const float* __restrict__ wT,
                                             float* __restrict__ qkvT){
  int b = blockIdx.x, o0 = blockIdx.y*64;
  int tid = threadIdx.x;
  int ot = tid&15, lt = tid>>4;
  __shared__ float4 LX[32][16];
  __shared__ float4 LW[32][16];
  const float4* xp4 = (const float4*)xp;
  const float4* wT4 = (const float4*)wT;
  float4 acc[4];
  #pragma unroll
  for (int j=0;j<4;++j) acc[j] = make_float4(0.f,0.f,0.f,0.f);
  for (int c0=0;c0<128;c0+=32){
    __syncthreads();
    #pragma unroll
    for (int p=0;p<2;++p){
      int e = tid + p*256; int kk=e>>4, q=e&15;
      LX[kk][q] = xp4[(size_t)b*2048 + (c0+kk)*16 + q];
      LW[kk][q] = wT4[(c0+kk)*64 + (o0>>2) + q];
    }
    __syncthreads();
    #pragma unroll
    for (int kk=0;kk<32;++kk){
      float4 x4 = LX[kk][lt];
      float4 w4 = LW[kk][ot];
      fma4(acc[0], w4, x4.x); fma4(acc[1], w4, x4.y);
      fma4(acc[2], w4, x4.z); fma4(acc[3], w4, x4.w);
    }
  }
  float4* qkvT4 = (float4*)qkvT;
  #pragma unroll
  for (int j=0;j<4;++j)
    qkvT4[((size_t)b*16384 + (lt*4+j)*256 + o0 + ot*4)>>2] = acc[j];
}

// ---------------- BN partial sums over rows of qkvT: grid (4 chG, 256 rowG) ----------------
__global__ __launch_bounds__(256) void k_bnsum(const float* __restrict__ qkvT, float2* __restrict__ part){
  int chG = blockIdx.x, rowG = blockIdx.y;
  int cl = threadIdx.x&63;
  int ch = chG*64 + cl;
  int rs = threadIdx.x>>6;
  float s=0.f, s2=0.f;
  for (int r = rowG*128 + rs; r < rowG*128 + 128; r += 4){
    float v = qkvT[(size_t)r*256 + ch]; s+=v; s2+=v*v;
  }
  __shared__ float S1[4][64], S2[4][64];
  S1[rs][cl]=s; S2[rs][cl]=s2; __syncthreads();
  if (rs==0){
    s  = S1[0][cl]+S1[1][cl]+S1[2][cl]+S1[3][cl];
    s2 = S2[0][cl]+S2[1][cl]+S2[2][cl]+S2[3][cl];
    part[(size_t)ch*256 + rowG] = make_float2(s, s2);
  }
}
__global__ void k_stats2(const float2* __restrict__ part, const float* __restrict__ g,
                         const float* __restrict__ bta, float2* __restrict__ st){
  int t = threadIdx.x;
  int chL = t>>3, seg = t&7;
  int ch = blockIdx.x*32 + chL;
  float s=0.f, s2=0.f;
  const float2* p = part + (size_t)ch*256 + seg*32;
  #pragma unroll 8
  for (int r=0;r<32;++r){ float2 q = p[r]; s+=q.x; s2+=q.y; }
  __shared__ float A[32][9], Bq[32][9];
  A[chL][seg]=s; Bq[chL][seg]=s2; __syncthreads();
  if (seg==0){
    #pragma unroll
    for (int k=1;k<8;++k){ s += A[chL][k]; s2 += Bq[chL][k]; }
    float m = s*(1.0f/32768.0f);
    float var = s2*(1.0f/32768.0f) - m*m;
    float sc = g[ch]/sqrtf(var + EPSV);
    st[ch] = make_float2(sc, bta[ch] - m*sc);
  }
}

// ---------------- qkvr: BN fold + resize 64->33 ----------------
__global__ __launch_bounds__(256) void k_qkvr(const float* __restrict__ qkvT, const float* __restrict__ W64,
                                              const float2* __restrict__ st, float* __restrict__ qkvrT){
  int b = blockIdx.x, ch = threadIdx.x;
  const float* base = qkvT + (size_t)b*16384 + ch;
  float xr[64];
  #pragma unroll
  for (int t=0;t<64;++t) xr[t] = base[t*256];
  float2 sb = st[ch];
  float* ob = qkvrT + (size_t)b*8448 + ch;
  for (int i=0;i<33;++i){
    const float4* wr = (const float4*)(W64 + i*64);
    float a = 0.f;
    #pragma unroll
    for (int q=0;q<16;++q){
      float4 w4 = wr[q];
      a += w4.x*xr[4*q] + w4.y*xr[4*q+1] + w4.z*xr[4*q+2] + w4.w*xr[4*q+3];
    }
    ob[i*256] = a*sb.x + sb.y;
  }
}

// ---------------- pos = resize(base_relative, (32,33,33)) separable ----------------
__global__ void k_pos1(const float* __restrict__ base, const float* __restrict__ W127, float* __restrict__ tmp){
  int id = blockIdx.x*256 + threadIdx.x;
  if (id >= 32*33*127) return;
  int c = id / 4191; int r = id - c*4191; int i = r / 127; int xx = r - i*127;
  const float* wr = W127 + i*127;
  const float* bc = base + c*16129 + xx;
  float a=0.f;
  for (int y=0;y<127;++y) a += wr[y]*bc[y*127];
  tmp[id] = a;
}
__global__ void k_pos2(const float* __restrict__ tmp, const float* __restrict__ W127, float* __restrict__ pos){
  int id = blockIdx.x*256 + threadIdx.x;
  if (id >= 32*33*33) return;
  int c = id / 1089; int r = id - c*1089; int i = r / 33; int j = r - i*33;
  const float* wr = W127 + j*127;
  const float* tc = tmp + c*4191 + i*127;
  float a=0.f;
  for (int xx=0;xx<127;++xx) a += wr[xx]*tc[xx];
  pos[id] = a;
}

// ---------------- keT[c][i][j] = k_e[c][j][i] ----------------
__global__ void k_keT(const float* __restrict__ pos, float* __restrict__ keT){
  int id = blockIdx.x*256 + threadIdx.x;
  if (id >= 8712) return;
  int c = id / 1089; int r = id - c*1089; int i = r / 33; int j = r - i*33;
  keT[id] = pos[(8+c)*1089 + j*33 + i];
}

// ---------------- sim = concat([qk, qr, kr]) + per-block stats partials ----------------
__global__ __launch_bounds__(256) void k_sim(const float* __restrict__ qkvrT, const float* __restrict__ pos,
                                             const float* __restrict__ keT,
                                             float* __restrict__ sim, float* __restrict__ part6){
  int b = blockIdx.x, g = blockIdx.y;
  __shared__ float lqa[264], lka[264];
  int tid = threadIdx.x;
  for (int e=tid;e<528;e+=256){
    int half = (e < 264) ? 0 : 1;
    int e2 = e - half*264;
    int c = e2/33, i = e2 - c*33;
    float v = qkvrT[(size_t)b*8448 + i*256 + (g*32 + half*8 + c)];
    if (half==0) lqa[e2]=v; else lka[e2]=v;
  }
  __syncthreads();
  float sqk=0.f,qqk=0.f,sqr=0.f,qqr=0.f,skr=0.f,qkr=0.f;
  for (int p=tid;p<1089;p+=256){
    int i = p/33, j = p - i*33;
    float qk=0.f, qr=0.f, kr=0.f;
    #pragma unroll
    for (int c=0;c<8;++c){
      float qa_ = lqa[c*33+i];
      float ka_ = lka[c*33+j];
      qk += qa_*ka_;
      qr += qa_*pos[c*1089 + i*33 + j];
      kr += ka_*keT[c*1089 + i*33 + j];
    }
    sim[(b*24 + g)*1089 + p] = qk;
    sim[(b*24 + 8 + g)*1089 + p] = qr;
    sim[(b*24 + 16 + g)*1089 + p] = kr;
    sqk+=qk; qqk+=qk*qk; sqr+=qr; qqr+=qr*qr; skr+=kr; qkr+=kr*kr;
  }
  __shared__ float red[6][256];
  red[0][tid]=sqk; red[1][tid]=qqk; red[2][tid]=sqr;
  red[3][tid]=qqr; red[4][tid]=skr; red[5][tid]=qkr;
  __syncthreads();
  for (int o=128;o>0;o>>=1){
    if (tid<o){
      #pragma unroll
      for (int c=0;c<6;++c) red[c][tid]+=red[c][tid+o];
    }
    __syncthreads();
  }
  if (tid<6) part6[(size_t)(b*8+g)*6 + tid] = red[tid][0];
}

// ---------------- simst from part6 ----------------
__global__ void k_sstB(const float* __restrict__ part6, const float* __restrict__ g,
                       const float* __restrict__ bta, float2* __restrict__ st){
  int nb = threadIdx.x;
  if (nb >= 192) return;
  int n = nb/24, ch = nb - n*24;
  int t3 = ch>>3, gg = ch&7;
  float s=0.f, s2=0.f;
  for (int w=0; w<64; ++w){
    const float* p = part6 + (size_t)((n*64+w)*8 + gg)*6 + 2*t3;
    s += p[0]; s2 += p[1];
  }
  float m = s*(1.0f/69696.0f);
  float var = s2*(1.0f/69696.0f) - m*m;
  float sc = g[ch]/sqrtf(var + EPSV);
  st[nb] = make_float2(sc, bta[ch] - m*sc);
}

// ---------------- velp: bf16 k-packed VeLT: [c16][kq9][i64][4t], k=4kq+t ----------------
__global__ void k_veLp(const float* __restrict__ pos, u16* __restrict__ velp){
  int id = blockIdx.x*256 + threadIdx.x;   // 16*9*64*4 = 36864
  if (id >= 36864) return;
  int t = id&3; int r = id>>2; int i = r&63; r >>= 6; int kq = r%9; int c = r/9;
  int k = kq*4 + t;
  float v = 0.f;
  if (k < 33){
    int i0; float fi; upfac(i, i0, fi);
    const float* P = pos + (16+c)*1089;
    v = (1.f-fi)*P[i0*33 + k] + fi*P[(i0+1)*33 + k];
  }
  velp[id] = f2b(v);
}

// ---------------- vap: k-packed Va: [b][g][c16][kq9] float4, element t = va[c][4kq+t] ----------------
__global__ void k_vap(const float* __restrict__ qkvrT, float* __restrict__ vap){
  int id = blockIdx.x*256 + threadIdx.x;   // 512*8*16*9*4 = 2359296
  if (id >= 2359296) return;
  int t = id&3; int r = id>>2; int kq = r%9; r /= 9; int c = r&15; r >>= 4; int g = r&7; int b = r>>3;
  int k = kq*4 + t;
  vap[id] = (k < 33) ? qkvrT[(size_t)b*8448 + k*256 + g*32 + 16 + c] : 0.f;
}

// ---------------- fused attention v4: prelerped-S LDS + global packed operands ----------------
// block = 2 bg x 2 channel-half waves. LDS: SL[2][64*34] only (17.4 KB).
// Phase A: 2 ds_read_b32 per j. Phase B: per 4-k group, Vap float4 (wave-uniform)
// + velp ushort4 (coalesced, bf16).
__global__ __launch_bounds__(256) void k_attn(const float* __restrict__ sim, const float2* __restrict__ simst,
                                              const float* __restrict__ vap, const u16* __restrict__ velp,
                                              float* __restrict__ so){
  int tid = threadIdx.x;
  int wv = tid >> 6;
  int i  = tid & 63;
  int pr = wv >> 1;          // bg slot within block
  int chh = wv & 1;          // channel half
  int bg = blockIdx.x*2 + pr;
  int b = bg>>3, g = bg&7;
  int n = b>>6;
  __shared__ float SL[2][2176];   // [i64][j33] pad->34, i-prelerped + BN-fused
  float* SLw = SL[pr];
  float2 sb0 = simst[n*24 + g], sb1 = simst[n*24 + 8 + g], sb2 = simst[n*24 + 16 + g];
  float badd = sb0.y + sb1.y + sb2.y;
  const float* s0 = sim + ((size_t)b*24 + g)*1089;
  int tl = (chh<<6) | i;     // 0..127 within the bg group
  for (int e=tl; e<2112; e+=128){
    int io = e/33, j = e - io*33;
    int i0; float fi; upfac(io, i0, fi);
    int o0 = i0*33 + j, o1 = o0 + 33;
    float a0 = s0[o0]*sb0.x + s0[o0+8712]*sb1.x + s0[o0+17424]*sb2.x;
    float a1 = s0[o1]*sb0.x + s0[o1+8712]*sb1.x + s0[o1+17424]*sb2.x;
    SLw[io*34 + j] = (1.f-fi)*a0 + fi*a1 + badd;
  }
  __syncthreads();

  // phase A: exp of the j-upsampled prelerped row
  const float* R = SLw + i*34;
  float p[64];
  float s = 0.f;
  #pragma unroll
  for (int j=0;j<64;++j){
    float fj = UT.fj[j]; int j0 = UT.j0[j];
    float su = (1.f-fj)*R[j0] + fj*R[j0+1];
    float e = expf(su);
    p[j] = e; s += e;
  }
  float inv = 1.f/s;

  // phase B: per 4-k group fold + both contractions
  float av[8], ae[8];
  #pragma unroll
  for (int c=0;c<8;++c){ av[c]=0.f; ae[c]=0.f; }
  const float4*  vap4 = (const float4*)vap + ((size_t)(b*8+g)*16 + chh*8)*9;  // [c8][kq9]
  const ushort4* ve4  = (const ushort4*)velp + (size_t)(chh*8)*9*64;          // [c8][kq9][i64]
  #pragma unroll
  for (int kq=0; kq<9; ++kq){
    float qkt[4];
    #pragma unroll
    for (int t=0;t<4;++t){
      int k = kq*4 + t;
      float q = 0.f;
      #pragma unroll
      for (int j=0;j<64;++j){
        if (UT.j0[j] == k)        q += p[j]*(1.f-UT.fj[j]);
        else if (UT.j0[j] == k-1) q += p[j]*UT.fj[j];
      }
      qkt[t] = q;
    }
    #pragma unroll
    for (int c=0;c<8;++c){
      float4 va = vap4[c*9 + kq];          // wave-uniform
      av[c] += qkt[0]*va.x + qkt[1]*va.y + qkt[2]*va.z + qkt[3]*va.w;
      ushort4 u = ve4[(c*9 + kq)*64 + i];  // coalesced 8B/lane
      ae[c] += qkt[0]*b2f(u.x) + qkt[1]*b2f(u.y) + qkt[2]*b2f(u.z) + qkt[3]*b2f(u.w);
    }
  }
  float* ob = so + (size_t)b*16384 + g*2048 + (chh*8)*128;
  #pragma unroll
  for (int c=0;c<8;++c) ob[c*128 + i]      = av[c]*inv;
  #pragma unroll
  for (int c=0;c<8;++c) ob[c*128 + 64 + i] = ae[c]*inv;
}

// ---------------- so BN stats, 2-stage ----------------
__global__ __launch_bounds__(256) void k_sost1(const float* __restrict__ so, float2* __restrict__ part){
  int ch = blockIdx.x, rowG = blockIdx.y;   // 256 x 8
  int tid = threadIdx.x;
  int rs = tid>>6, l = tid&63;
  float s=0.f, s2=0.f;
  for (int r = rowG*64 + rs; r < rowG*64 + 64; r += 4){
    float v = so[((size_t)r*256 + ch)*64 + l]; s+=v; s2+=v*v;
  }
  __shared__ float S1[256], S2[256];
  S1[tid]=s; S2[tid]=s2; __syncthreads();
  for (int o=128;o>0;o>>=1){ if(tid<o){ S1[tid]+=S1[tid+o]; S2[tid]+=S2[tid+o]; } __syncthreads(); }
  if (tid==0) part[ch*8 + rowG] = make_float2(S1[0], S2[0]);
}
__global__ void k_sost2(const float2* __restrict__ part, const float* __restrict__ g,
                        const float* __restrict__ bta, float2* __restrict__ st){
  int ch = threadIdx.x;   // 256
  float s=0.f, s2=0.f;
  #pragma unroll
  for (int r=0;r<8;++r){ float2 p = part[ch*8 + r]; s+=p.x; s2+=p.y; }
  float m = s*(1.0f/32768.0f);
  float var = s2*(1.0f/32768.0f) - m*m;
  float sc = g[ch]/sqrtf(var + EPSV);
  st[ch] = make_float2(sc, bta[ch] - m*sc);
}

// ---------------- BN(so) + pair-sum + transpose -> o ----------------
__global__ void k_o(const float* __restrict__ so, const float2* __restrict__ st, float* __restrict__ o){
  int id = blockIdx.x*256 + threadIdx.x;
  int w = id&63, h=(id>>6)&63, oc=(id>>12)&127, n=id>>19;
  int b = n*64 + w;
  float2 s0 = st[2*oc], s1 = st[2*oc+1];
  float v0 = so[b*16384 + (2*oc)*64 + h];
  float v1 = so[b*16384 + (2*oc+1)*64 + h];
  o[id] = v0*s0.x + s0.y + v1*s1.x + s1.y;
}

// ---------------- spatial block ----------------
__device__ __forceinline__ float xo_val(const float* __restrict__ o, int n, int c, int h, int w){
  if (c >= 40) return o[((n*128 + c)*64 + h)*64 + w];
  int grp = c / 10;
  int cc = c - grp*10;
  int base = (n*128 + cc)*64;
  if (grp==0) return (w>=2) ? o[(base + h)*64 + (w-2)] : 0.f;
  if (grp==1) return (w<62) ? o[(base + h)*64 + (w+2)] : 0.f;
  if (grp==2) return (h>=2) ? o[(base + (h-2))*64 + w] : 0.f;
  return (h<62) ? o[(base + (h+2))*64 + w] : 0.f;
}

__global__ __launch_bounds__(256) void k_instats(const float* __restrict__ o, const float* __restrict__ g,
                                                 const float* __restrict__ bta, float2* __restrict__ st){
  int nb = blockIdx.x; int n = nb>>7, c = nb&127;
  int t = threadIdx.x;
  float s=0.f,s2=0.f;
  for (int e=t;e<4096;e+=256){
    int h=e>>6, w=e&63;
    float v = xo_val(o,n,c,h,w);
    s+=v; s2+=v*v;
  }
  __shared__ float rs[256], rq[256];
  rs[t]=s; rq[t]=s2; __syncthreads();
  for (int oo=128;oo>0;oo>>=1){ if(t<oo){ rs[t]+=rs[t+oo]; rq[t]+=rq[t+oo]; } __syncthreads(); }
  if (t==0){
    float m = rs[0]*(1.0f/4096.0f);
    float var = rq[0]*(1.0f/4096.0f) - m*m;
    float sc = g[c]/sqrtf(var + EPSV);
    st[nb] = make_float2(sc, bta[c] - m*sc);
  }
}

// ---------------- fused: instance-norm(xo) + transpose -> xnT bf16 [n][hw][c] ----------------
__global__ __launch_bounds__(256) void k_xnt(const float* __restrict__ o, const float2* __restrict__ st,
                                             u16* __restrict__ xnT){
  __shared__ float T[64][65];
  int h = blockIdx.x&63, c0 = ((blockIdx.x>>6)&1)*64, n = blockIdx.x>>7;
  int tid = threadIdx.x;
  for (int e=tid;e<4096;e+=256){
    int cL = e>>6, w = e&63;
    float2 sb = st[n*128 + c0+cL];
    T[cL][w] = xo_val(o, n, c0+cL, h, w)*sb.x + sb.y;
  }
  __syncthreads();
  for (int e=tid;e<4096;e+=256){
    int wL = e>>6, cL = e&63;
    xnT[((size_t)(n*4096 + h*64 + wL))*128 + c0 + cL] = f2b(T[cL][wL]);
  }
}

// ---------------- MFMA bf16 GEMM core ----------------
__global__ __launch_bounds__(256) void k_mlp1(const u16* __restrict__ xnT, const u16* __restrict__ w1b,
                                              u16* __restrict__ h1T){
  int hw0 = blockIdx.x*128, co0 = blockIdx.y*128, n = blockIdx.z;
  int tid = threadIdx.x;
  int wv = tid>>6, l = tid&63;
  int wm = (wv>>1)*64, wn = (wv&1)*64;
  int lr = l&15, lq = l>>4;
  __shared__ u16 As[128*40];
  __shared__ u16 Bs[128*40];
  f32x4 acc[4][4];
  #pragma unroll
  for (int mi=0;mi<4;++mi)
    #pragma unroll
    for (int ni=0;ni<4;++ni) acc[mi][ni] = (f32x4){0.f,0.f,0.f,0.f};
  const u16* Ag = xnT + ((size_t)(n*4096 + hw0))*128;
  const u16* Bg = w1b + (size_t)co0*128;
  for (int ks=0; ks<128; ks+=32){
    __syncthreads();
    #pragma unroll
    for (int p=0;p<2;++p){
      int e = tid + p*256; int row = e>>2, q = e&3;
      *(uint4*)&As[row*40 + q*8] = *(const uint4*)&Ag[(size_t)row*128 + ks + q*8];
      *(uint4*)&Bs[row*40 + q*8] = *(const uint4*)&Bg[(size_t)row*128 + ks + q*8];
    }
    __syncthreads();
    bf16x8 af[4], bfr[4];
    #pragma unroll
    for (int mi=0;mi<4;++mi) af[mi] = *(const bf16x8*)&As[(wm + mi*16 + lr)*40 + lq*8];
    #pragma unroll
    for (int ni=0;ni<4;++ni) bfr[ni] = *(const bf16x8*)&Bs[(wn + ni*16 + lr)*40 + lq*8];
    #pragma unroll
    for (int mi=0;mi<4;++mi)
      #pragma unroll
      for (int ni=0;ni<4;++ni)
        acc[mi][ni] = __builtin_amdgcn_mfma_f32_16x16x32_bf16(af[mi], bfr[ni], acc[mi][ni], 0,0,0);
  }
  u16* ob = h1T + ((size_t)(n*4096 + hw0 + wm))*512 + co0 + wn;
  #pragma unroll
  for (int mi=0;mi<4;++mi)
    #pragma unroll
    for (int r=0;r<4;++r){
      int row = mi*16 + lq*4 + r;
      #pragma unroll
      for (int ni=0;ni<4;++ni){
        float v = acc[mi][ni][r];
        v = 0.5f*v*(1.0f + erff(v*0.70710678f));
        ob[(size_t)row*512 + ni*16 + lr] = f2b(v);
      }
    }
}

__global__ __launch_bounds__(256) void k_mlp2(const u16* __restrict__ w2b, const u16* __restrict__ h1T,
                                              float* __restrict__ out){
  int hw0 = blockIdx.x*128, n = blockIdx.z;
  int tid = threadIdx.x;
  int wv = tid>>6, l = tid&63;
  int wm = (wv>>1)*64, wn = (wv&1)*64;
  int lr = l&15, lq = l>>4;
  __shared__ u16 As[128*40];
  __shared__ u16 Bs[128*40];
  f32x4 acc[4][4];
  #pragma unroll
  for (int mi=0;mi<4;++mi)
    #pragma unroll
    for (int ni=0;ni<4;++ni) acc[mi][ni] = (f32x4){0.f,0.f,0.f,0.f};
  const u16* Ag = w2b;
  const u16* Bg = h1T + ((size_t)(n*4096 + hw0))*512;
  for (int ks=0; ks<512; ks+=32){
    __syncthreads();
    #pragma unroll
    for (int p=0;p<2;++p){
      int e = tid + p*256; int row = e>>2, q = e&3;
      *(uint4*)&As[row*40 + q*8] = *(const uint4*)&Ag[(size_t)row*512 + ks + q*8];
      *(uint4*)&Bs[row*40 + q*8] = *(const uint4*)&Bg[(size_t)row*512 + ks + q*8];
    }
    __syncthreads();
    bf16x8 af[4], bfr[4];
    #pragma unroll
    for (int mi=0;mi<4;++mi) af[mi] = *(const bf16x8*)&As[(wm + mi*16 + lr)*40 + lq*8];
    #pragma unroll
    for (int ni=0;ni<4;++ni) bfr[ni] = *(const bf16x8*)&Bs[(wn + ni*16 + lr)*40 + lq*8];
    #pragma unroll
    for (int mi=0;mi<4;++mi)
      #pragma unroll
      for (int ni=0;ni<4;++ni)
        acc[mi][ni] = __builtin_amdgcn_mfma_f32_16x16x32_bf16(af[mi], bfr[ni], acc[mi][ni], 0,0,0);
  }
  #pragma unroll
  for (int mi=0;mi<4;++mi)
    #pragma unroll
    for (int r=0;r<4;++r){
      int cout = wm + mi*16 + lq*4 + r;
      #pragma unroll
      for (int ni=0;ni<4;++ni){
        size_t idx = ((size_t)(n*128 + cout))*4096 + hw0 + wn + ni*16 + lr;
        out[idx] = acc[mi][ni][r] + out[idx];
      }
    }
}

extern "C" void kernel_launch(void* const* d_in, const int* in_sizes, int n_in,
                              void* d_out, int out_size, void* d_ws, size_t ws_size,
                              hipStream_t stream) {
  (void)in_sizes; (void)n_in; (void)out_size; (void)ws_size;
  const float* x       = (const float*)d_in[0];
  const float* qkvw    = (const float*)d_in[1];
  const float* bng     = (const float*)d_in[2];
  const float* bnb     = (const float*)d_in[3];
  const float* baserel = (const float*)d_in[4];
  const float* simg    = (const float*)d_in[5];
  const float* simb    = (const float*)d_in[6];
  const float* outg    = (const float*)d_in[7];
  const float* outb    = (const float*)d_in[8];
  const float* ing     = (const float*)d_in[9];
  const float* inb     = (const float*)d_in[10];
  const float* w1      = (const float*)d_in[11];
  const float* w2      = (const float*)d_in[12];

  float* ws = (float*)d_ws;
  float*  W127  = ws + F_W127;
  float*  W64   = ws + F_W64;
  float2* qkvst = (float2*)(ws + F_QKVST);
  float2* simst = (float2*)(ws + F_SIMST);
  float2* sost  = (float2*)(ws + F_SOST);
  float2* inst  = (float2*)(ws + F_INST);
  float*  postmp= ws + F_POSTMP;
  float*  pos   = ws + F_POS;
  float*  qkvT  = ws + F_QKV;
  float*  qkvrT = ws + F_QKVR;
  float*  sim   = ws + F_SIM;
  float*  part6 = ws + F_PART6;
  float2* sopart= (float2*)(ws + F_PART6);   // reuse after k_attn (part6/vap dead)
  float*  vap   = ws + F_VAP;
  u16*    velp  = (u16*)(ws + F_VEH);
  u16*    xnT   = (u16*)(ws + F_XNT);
  float*  keT   = ws + F_KET;
  float*  so    = ws + F_SO;
  float*  xp    = ws + F_XP;
  float2* bnp   = (float2*)(ws + F_BNP);
  u16*    h1T   = (u16*)(ws + F_H1);
  float*  wT    = ws + F_WT;
  u16*    w1b   = (u16*)(ws + F_W1B);
  u16*    w2b   = (u16*)(ws + F_W2B);
  float*  out   = (float*)d_out;

  k_tables  <<<dim3(1),        dim3(128), 0, stream>>>(W127, W64);
  k_tr      <<<dim3(8,4),      dim3(256), 0, stream>>>(qkvw, wT, 256, 128);
  k_xt      <<<dim3(1024),     dim3(256), 0, stream>>>(x, xp);
  k_qkv     <<<dim3(512,4),    dim3(256), 0, stream>>>(xp, wT, qkvT);
  k_bnsum   <<<dim3(4,256),    dim3(256), 0, stream>>>(qkvT, bnp);
  k_stats2  <<<dim3(8),        dim3(256), 0, stream>>>(bnp, bng, bnb, qkvst);
  k_qkvr    <<<dim3(512),      dim3(256), 0, stream>>>(qkvT, W64, qkvst, qkvrT);
  k_vap     <<<dim3(9216),     dim3(256), 0, stream>>>(qkvrT, vap);
  k_pos1    <<<dim3(524),      dim3(256), 0, stream>>>(baserel, W127, postmp);
  k_pos2    <<<dim3(137),      dim3(256), 0, stream>>>(postmp, W127, pos);
  k_keT     <<<dim3(35),       dim3(256), 0, stream>>>(pos, keT);
  k_veLp    <<<dim3(144),      dim3(256), 0, stream>>>(pos, velp);
  k_cvtb    <<<dim3(256),      dim3(256), 0, stream>>>(w1, w1b, 65536);
  k_cvtb    <<<dim3(256),      dim3(256), 0, stream>>>(w2, w2b, 65536);
  k_sim     <<<dim3(512,8),    dim3(256), 0, stream>>>(qkvrT, pos, keT, sim, part6);
  k_sstB    <<<dim3(1),        dim3(192), 0, stream>>>(part6, simg, simb, simst);
  k_attn    <<<dim3(2048),     dim3(256), 0, stream>>>(sim, simst, vap, velp, so);
  k_sost1   <<<dim3(256,8),    dim3(256), 0, stream>>>(so, sopart);
  k_sost2   <<<dim3(1),        dim3(256), 0, stream>>>(sopart, outg, outb, sost);
  k_o       <<<dim3(16384),    dim3(256), 0, stream>>>(so, sost, out);
  k_instats <<<dim3(1024),     dim3(256), 0, stream>>>(out, ing, inb, inst);
  k_xnt     <<<dim3(1024),     dim3(256), 0, stream>>>(out, inst, xnT);
  k_mlp1    <<<dim3(32,4,8),   dim3(256), 0, stream>>>(xnT, w1b, h1T);
  k_mlp2    <<<dim3(32,1,8),   dim3(256), 0, stream>>>(w2b, h1T, out);
}